// Round 7
// baseline (57.959 us; speedup 1.0000x reference)
//
#include <hip/hip_runtime.h>
#include <hip/hip_bf16.h>

// MHSA window attention: B=64 windows, H=32 heads, N=256 tokens, D=16.
// One block per (b,h): 256 threads = 4 waves; wave w handles q-tiles w and w+4,
// processed INTERLEAVED in one kv loop (shared K/V fragments, double ILP).
// mfma_f32_32x32x16_bf16: K=16 == head_dim exactly (no padding, no idle lanes).
// Swapped QK^T -> softmax lane-local; P stays in registers (permlane32_swap);
// V^T row 16 = ones -> PV accumulator reg8 IS the softmax denominator.

typedef short bf16x8 __attribute__((ext_vector_type(8)));
typedef float f32x16 __attribute__((ext_vector_type(16)));

__device__ __forceinline__ unsigned int pk2(float a, float b) {
  __hip_bfloat162 hh = __float22bfloat162_rn(float2{a, b});   // v_cvt_pk_bf16_f32
  unsigned int u; __builtin_memcpy(&u, &hh, 4); return u;
}

#if __has_builtin(__builtin_amdgcn_permlane32_swap)
typedef int i32x2_t __attribute__((ext_vector_type(2)));
__device__ __forceinline__ void swap_halves(unsigned x, unsigned y, unsigned& ox, unsigned& oy) {
  i32x2_t r = __builtin_amdgcn_permlane32_swap((int)x, (int)y, false, false);
  ox = (unsigned)r.x;   // lanes<32: x.lo | lanes>=32: y.lo
  oy = (unsigned)r.y;   // lanes<32: x.hi | lanes>=32: y.hi
}
#else
__device__ __forceinline__ void swap_halves(unsigned x, unsigned y, unsigned& ox, unsigned& oy) {
  const int hi = (threadIdx.x & 63) >> 5;
  unsigned tx = (unsigned)__shfl_xor((int)x, 32);
  unsigned ty = (unsigned)__shfl_xor((int)y, 32);
  ox = hi ? ty : x;
  oy = hi ? y : tx;
}
#endif

__global__ __launch_bounds__(256, 4)
void mhsa_kernel(const float* __restrict__ inp, const float* __restrict__ table,
                 float* __restrict__ out) {
  const int bh = blockIdx.x;
  const int b = bh >> 5, h = bh & 31;
  const int t = threadIdx.x;
  const int l = t & 63;
  const int w = t >> 6;
  const int q32 = l & 31;     // MFMA col (q index); also A-operand row role
  const int hi = l >> 5;      // k-group / half-wave

  __shared__ __align__(16) short KF[8][64][8];   // K fragment-order: [kv-tile32][lane][8]
  __shared__ __align__(16) short VF[16][34][8];  // V^T frag-order: [kv-chunk16][hik*17 + d][8]; d=16 row = ones
  __shared__ float tbl[128];                     // bias column * log2(e)

  if (t < 127) tbl[t] = table[t * 32 + h] * 1.4426950408889634f;
  {
    // ones rows (sum trick): VF[kb][hv*17 + 16][j] = 1.0bf16, 256 slots = 1/thread
    const int kb = t >> 4, hv = (t >> 3) & 1, j = t & 7;
    VF[kb][hv * 17 + 16][j] = (short)0x3F80;
  }

  const float* gbase = inp + (size_t)b * (256 * 1536) + h * 16;

  // Q prefetch for BOTH q-tiles (latency hides under K/V staging/convert)
  float4 qa0, qb0, qa1, qb1;
  {
    const float* qp0 = gbase + (size_t)(w * 32 + q32) * 1536 + hi * 8;
    const float* qp1 = gbase + (size_t)((w + 4) * 32 + q32) * 1536 + hi * 8;
    qa0 = *(const float4*)qp0;
    qb0 = *(const float4*)(qp0 + 4);
    qa1 = *(const float4*)qp1;
    qb1 = *(const float4*)(qp1 + 4);
  }

  // K/V staging into fragment-order LDS
  {
    const int row0 = t >> 2, c4 = t & 3;
    #pragma unroll
    for (int it = 0; it < 4; ++it) {
      const int row = it * 64 + row0;
      const float* p = gbase + (size_t)row * 1536 + c4 * 4;
      float4 kv = *(const float4*)(p + 512);
      float4 vv = *(const float4*)(p + 1024);
      // KF[row>>5][(c4>>1)*32 + (row&31)][(c4&1)*4 ..]
      short* kdst = &KF[0][0][0] + (row >> 5) * 512 + ((c4 >> 1) * 32 + (row & 31)) * 8 + (c4 & 1) * 4;
      *(int2*)kdst = make_int2(pk2(kv.x, kv.y), pk2(kv.z, kv.w));
      // VF[row>>4][((row>>3)&1)*17 + d][row&7] for d = c4*4..c4*4+3
      unsigned int v01 = pk2(vv.x, vv.y), v23 = pk2(vv.z, vv.w);
      short* vdst = &VF[0][0][0] + (row >> 4) * 272 + (((row >> 3) & 1) * 17 + c4 * 4) * 8 + (row & 7);
      vdst[0]  = (short)(v01 & 0xffff);
      vdst[8]  = (short)(v01 >> 16);
      vdst[16] = (short)(v23 & 0xffff);
      vdst[24] = (short)(v23 >> 16);
    }
  }

  // Convert Q to bf16 B-frags for both tiles
  bf16x8 q8A, q8B;
  {
    unsigned int qw[4] = { pk2(qa0.x, qa0.y), pk2(qa0.z, qa0.w),
                           pk2(qb0.x, qb0.y), pk2(qb0.z, qb0.w) };
    __builtin_memcpy(&q8A, qw, 16);
    unsigned int qx[4] = { pk2(qa1.x, qa1.y), pk2(qa1.z, qa1.w),
                           pk2(qb1.x, qb1.y), pk2(qb1.z, qb1.w) };
    __builtin_memcpy(&q8B, qx, 16);
  }

  __syncthreads();

  const float scale2 = 0.17677669529663687f * 1.4426950408889634f;  // 32^-0.5 * log2e
  const f32x16 z16 = {0.f};
  const short* kfb = &KF[0][0][0] + l * 8;                       // linear: conflict-free
  const int vslot = hi * 17 + (q32 > 16 ? 16 : q32);             // d row (>=16 -> ones row)
  const short* vfb = &VF[0][0][0] + vslot * 8;

  const int qbaseA = w * 32;
  const int qbaseB = (w + 4) * 32;
  const int bbA = (qbaseA >> 2) + (q32 >> 2) + 63 - hi;
  const int bbB = (qbaseB >> 2) + (q32 >> 2) + 63 - hi;

  f32x16 oA = z16, oB = z16;

  #pragma unroll 2
  for (int kt = 0; kt < 8; ++kt) {
    // Shared fragments for both q-tiles
    bf16x8 kf = *(const bf16x8*)(kfb + kt * 512);
    bf16x8 v0 = *(const bf16x8*)(vfb + (kt * 2 + 0) * 272);
    bf16x8 v1 = *(const bf16x8*)(vfb + (kt * 2 + 1) * 272);

    // S^T tiles (32kv x 32q): rows kv = kt*32 + (reg&3)+8*(reg>>2)+4*hi, col q
    f32x16 sA = __builtin_amdgcn_mfma_f32_32x32x16_bf16(kf, q8A, z16, 0, 0, 0);
    f32x16 sB = __builtin_amdgcn_mfma_f32_32x32x16_bf16(kf, q8B, z16, 0, 0, 0);

    // bias + exp2 (no max-sub: logits bounded), pack to bf16 pairs
    unsigned int wdA[8], wdB[8];
    #pragma unroll
    for (int m = 0; m < 4; ++m) {
      const float biasA = tbl[bbA - kt * 8 - 2 * m];
      const float biasB = tbl[bbB - kt * 8 - 2 * m];
      float a0 = __builtin_amdgcn_exp2f(fmaf(sA[4 * m + 0], scale2, biasA));
      float a1 = __builtin_amdgcn_exp2f(fmaf(sA[4 * m + 1], scale2, biasA));
      float a2 = __builtin_amdgcn_exp2f(fmaf(sA[4 * m + 2], scale2, biasA));
      float a3 = __builtin_amdgcn_exp2f(fmaf(sA[4 * m + 3], scale2, biasA));
      wdA[2 * m]     = pk2(a0, a1);
      wdA[2 * m + 1] = pk2(a2, a3);
      float e0 = __builtin_amdgcn_exp2f(fmaf(sB[4 * m + 0], scale2, biasB));
      float e1 = __builtin_amdgcn_exp2f(fmaf(sB[4 * m + 1], scale2, biasB));
      float e2 = __builtin_amdgcn_exp2f(fmaf(sB[4 * m + 2], scale2, biasB));
      float e3 = __builtin_amdgcn_exp2f(fmaf(sB[4 * m + 3], scale2, biasB));
      wdB[2 * m]     = pk2(e0, e1);
      wdB[2 * m + 1] = pk2(e2, e3);
    }

    // Assemble PV B-frags (P^T[kv16][q]) via half-wave swaps
    unsigned f0, f1, f2, f3;
    bf16x8 pA0, pA1, pB0, pB1;
    swap_halves(wdA[0], wdA[2], f0, f2);
    swap_halves(wdA[1], wdA[3], f1, f3);
    { unsigned a4[4] = { f0, f1, f2, f3 }; __builtin_memcpy(&pA0, a4, 16); }
    swap_halves(wdA[4], wdA[6], f0, f2);
    swap_halves(wdA[5], wdA[7], f1, f3);
    { unsigned a4[4] = { f0, f1, f2, f3 }; __builtin_memcpy(&pA1, a4, 16); }
    swap_halves(wdB[0], wdB[2], f0, f2);
    swap_halves(wdB[1], wdB[3], f1, f3);
    { unsigned a4[4] = { f0, f1, f2, f3 }; __builtin_memcpy(&pB0, a4, 16); }
    swap_halves(wdB[4], wdB[6], f0, f2);
    swap_halves(wdB[5], wdB[7], f1, f3);
    { unsigned a4[4] = { f0, f1, f2, f3 }; __builtin_memcpy(&pB1, a4, 16); }

    // out^T += V^T * P^T  (A row 16 = ones -> row-sum lands in reg8, hi=0)
    oA = __builtin_amdgcn_mfma_f32_32x32x16_bf16(v0, pA0, oA, 0, 0, 0);
    oA = __builtin_amdgcn_mfma_f32_32x32x16_bf16(v1, pA1, oA, 0, 0, 0);
    oB = __builtin_amdgcn_mfma_f32_32x32x16_bf16(v0, pB0, oB, 0, 0, 0);
    oB = __builtin_amdgcn_mfma_f32_32x32x16_bf16(v1, pB1, oB, 0, 0, 0);
  }

  // denominator: C row16 = reg8 of hi=0 lanes; broadcast to both halves
  {
    const float inv = 1.0f / __shfl(oA[8], q32);
    float* op = out + (size_t)(b * 256 + qbaseA + q32) * 512 + h * 16 + hi * 4;
    float4 r0 = { oA[0] * inv, oA[1] * inv, oA[2] * inv, oA[3] * inv };
    float4 r1 = { oA[4] * inv, oA[5] * inv, oA[6] * inv, oA[7] * inv };
    *(float4*)op = r0;
    *(float4*)(op + 8) = r1;
  }
  {
    const float inv = 1.0f / __shfl(oB[8], q32);
    float* op = out + (size_t)(b * 256 + qbaseB + q32) * 512 + h * 16 + hi * 4;
    float4 r0 = { oB[0] * inv, oB[1] * inv, oB[2] * inv, oB[3] * inv };
    float4 r1 = { oB[4] * inv, oB[5] * inv, oB[6] * inv, oB[7] * inv };
    *(float4*)op = r0;
    *(float4*)(op + 8) = r1;
  }
}

extern "C" void kernel_launch(void* const* d_in, const int* in_sizes, int n_in,
                              void* d_out, int out_size, void* d_ws, size_t ws_size,
                              hipStream_t stream) {
  (void)in_sizes; (void)n_in; (void)out_size; (void)d_ws; (void)ws_size;
  const float* inp = (const float*)d_in[0];
  const float* tbl = (const float*)d_in[1];
  float* out = (float*)d_out;
  hipLaunchKernelGGL(mhsa_kernel, dim3(2048), dim3(256), 0, stream, inp, tbl, out);
}

// Round 8
// 47.357 us; speedup vs baseline: 1.2239x; 1.2239x over previous
//
#include <hip/hip_runtime.h>
#include <hip/hip_bf16.h>

// MHSA window attention: B=64 windows, H=32 heads, N=256 tokens, D=16.
// One block per (b,h): 256 threads = 4 waves; wave w handles q-tiles w and w+4.
// mfma_f32_32x32x16_bf16 (K=16 == head_dim, no padding). Swapped QK^T ->
// softmax lane-local; P stays in registers (permlane32_swap); V^T row 16 =
// ones -> PV accumulator reg8 IS the softmax denominator.
// 2-phase staging pipeline: compute kv[0:128] while kv[128:256] loads in flight.

typedef short bf16x8 __attribute__((ext_vector_type(8)));
typedef float f32x16 __attribute__((ext_vector_type(16)));

__device__ __forceinline__ unsigned int pk2(float a, float b) {
  __hip_bfloat162 hh = __float22bfloat162_rn(float2{a, b});   // v_cvt_pk_bf16_f32
  unsigned int u; __builtin_memcpy(&u, &hh, 4); return u;
}

#if __has_builtin(__builtin_amdgcn_permlane32_swap)
typedef int i32x2_t __attribute__((ext_vector_type(2)));
__device__ __forceinline__ void swap_halves(unsigned x, unsigned y, unsigned& ox, unsigned& oy) {
  i32x2_t r = __builtin_amdgcn_permlane32_swap((int)x, (int)y, false, false);
  ox = (unsigned)r.x;
  oy = (unsigned)r.y;
}
#else
__device__ __forceinline__ void swap_halves(unsigned x, unsigned y, unsigned& ox, unsigned& oy) {
  const int hi = (threadIdx.x & 63) >> 5;
  unsigned tx = (unsigned)__shfl_xor((int)x, 32);
  unsigned ty = (unsigned)__shfl_xor((int)y, 32);
  ox = hi ? ty : x;
  oy = hi ? y : tx;
}
#endif

__global__ __launch_bounds__(256, 4)
void mhsa_kernel(const float* __restrict__ inp, const float* __restrict__ table,
                 float* __restrict__ out) {
  const int bh = blockIdx.x;
  const int b = bh >> 5, h = bh & 31;
  const int t = threadIdx.x;
  const int l = t & 63;
  const int w = t >> 6;
  const int q32 = l & 31;     // MFMA col (q index)
  const int hi = l >> 5;      // half-wave

  __shared__ __align__(16) short KF[8][64][8];   // K fragment-order: [kv-tile32][lane][8]
  __shared__ __align__(16) short VF[16][34][8];  // V^T frag-order; d=16 row = ones
  __shared__ float tbl[128];                     // bias column * log2(e)

  const float* gbase = inp + (size_t)b * (256 * 1536) + h * 16;
  const int row0 = t >> 2, c4 = t & 3;

  // ---- Issue ALL global loads up front (priority order) ----
  const float* p0 = gbase + (size_t)(row0      ) * 1536 + c4 * 4;
  const float* p1 = gbase + (size_t)(row0 +  64) * 1536 + c4 * 4;
  const float* p2 = gbase + (size_t)(row0 + 128) * 1536 + c4 * 4;
  const float* p3 = gbase + (size_t)(row0 + 192) * 1536 + c4 * 4;
  float4 ka = *(const float4*)(p0 + 512);
  float4 va = *(const float4*)(p0 + 1024);
  float4 kb_ = *(const float4*)(p1 + 512);
  float4 vb_ = *(const float4*)(p1 + 1024);
  const float* qp0 = gbase + (size_t)(w * 32 + q32) * 1536 + hi * 8;
  const float* qp1 = gbase + (size_t)((w + 4) * 32 + q32) * 1536 + hi * 8;
  float4 qa0 = *(const float4*)qp0;
  float4 qb0 = *(const float4*)(qp0 + 4);
  float4 qa1 = *(const float4*)qp1;
  float4 qb1 = *(const float4*)(qp1 + 4);
  float4 kc = *(const float4*)(p2 + 512);
  float4 vc = *(const float4*)(p2 + 1024);
  float4 kd = *(const float4*)(p3 + 512);
  float4 vd = *(const float4*)(p3 + 1024);

  if (t < 127) tbl[t] = table[t * 32 + h] * 1.4426950408889634f;
  {
    // ones rows (sum trick): VF[kb][hv*17 + 16][j] = 1.0bf16
    const int kb = t >> 4, hv = (t >> 3) & 1, j = t & 7;
    VF[kb][hv * 17 + 16][j] = (short)0x3F80;
  }

  auto stage = [&](int row, const float4& kv, const float4& vv) {
    short* kdst = &KF[0][0][0] + (row >> 5) * 512 + ((c4 >> 1) * 32 + (row & 31)) * 8 + (c4 & 1) * 4;
    *(int2*)kdst = make_int2(pk2(kv.x, kv.y), pk2(kv.z, kv.w));
    unsigned int v01 = pk2(vv.x, vv.y), v23 = pk2(vv.z, vv.w);
    short* vdst = &VF[0][0][0] + (row >> 4) * 272 + (((row >> 3) & 1) * 17 + c4 * 4) * 8 + (row & 7);
    vdst[0]  = (short)(v01 & 0xffff);
    vdst[8]  = (short)(v01 >> 16);
    vdst[16] = (short)(v23 & 0xffff);
    vdst[24] = (short)(v23 >> 16);
  };

  // Phase-1 staging: kv rows 0..127
  stage(row0, ka, va);
  stage(row0 + 64, kb_, vb_);

  // Q -> bf16 B-frags for both tiles
  bf16x8 q8A, q8B;
  {
    unsigned int qw[4] = { pk2(qa0.x, qa0.y), pk2(qa0.z, qa0.w),
                           pk2(qb0.x, qb0.y), pk2(qb0.z, qb0.w) };
    __builtin_memcpy(&q8A, qw, 16);
    unsigned int qx[4] = { pk2(qa1.x, qa1.y), pk2(qa1.z, qa1.w),
                           pk2(qb1.x, qb1.y), pk2(qb1.z, qb1.w) };
    __builtin_memcpy(&q8B, qx, 16);
  }

  __syncthreads();   // phase-1 data ready

  const float scale2 = 0.17677669529663687f * 1.4426950408889634f;  // 32^-0.5 * log2e
  const f32x16 z16 = {0.f};
  const short* kfb = &KF[0][0][0] + l * 8;                       // linear: conflict-free
  const int vslot = hi * 17 + (q32 > 16 ? 16 : q32);             // d row (>=16 -> ones row)
  const short* vfb = &VF[0][0][0] + vslot * 8;

  const int qbaseA = w * 32;
  const int qbaseB = (w + 4) * 32;
  const int bbA = (qbaseA >> 2) + (q32 >> 2) + 63 - hi;
  const int bbB = (qbaseB >> 2) + (q32 >> 2) + 63 - hi;

  f32x16 oA = z16, oB = z16;

  auto tile_step = [&](int kt, const bf16x8& q8, f32x16& oacc, int bb) {
    bf16x8 kf = *(const bf16x8*)(kfb + kt * 512);
    f32x16 s = __builtin_amdgcn_mfma_f32_32x32x16_bf16(kf, q8, z16, 0, 0, 0);
    unsigned int wd[8];
    #pragma unroll
    for (int m = 0; m < 4; ++m) {
      const float bias = tbl[bb - kt * 8 - 2 * m];
      float e0 = __builtin_amdgcn_exp2f(fmaf(s[4 * m + 0], scale2, bias));
      float e1 = __builtin_amdgcn_exp2f(fmaf(s[4 * m + 1], scale2, bias));
      float e2 = __builtin_amdgcn_exp2f(fmaf(s[4 * m + 2], scale2, bias));
      float e3 = __builtin_amdgcn_exp2f(fmaf(s[4 * m + 3], scale2, bias));
      wd[2 * m]     = pk2(e0, e1);
      wd[2 * m + 1] = pk2(e2, e3);
    }
    unsigned f0, f1, f2, f3;
    bf16x8 pf0, pf1;
    swap_halves(wd[0], wd[2], f0, f2);
    swap_halves(wd[1], wd[3], f1, f3);
    { unsigned a4[4] = { f0, f1, f2, f3 }; __builtin_memcpy(&pf0, a4, 16); }
    swap_halves(wd[4], wd[6], f0, f2);
    swap_halves(wd[5], wd[7], f1, f3);
    { unsigned a4[4] = { f0, f1, f2, f3 }; __builtin_memcpy(&pf1, a4, 16); }
    bf16x8 v0 = *(const bf16x8*)(vfb + (kt * 2 + 0) * 272);
    bf16x8 v1 = *(const bf16x8*)(vfb + (kt * 2 + 1) * 272);
    oacc = __builtin_amdgcn_mfma_f32_32x32x16_bf16(v0, pf0, oacc, 0, 0, 0);
    oacc = __builtin_amdgcn_mfma_f32_32x32x16_bf16(v1, pf1, oacc, 0, 0, 0);
  };

  // ---- Phase 1 compute: kt 0..3, both tiles (second-half loads in flight) ----
  #pragma unroll
  for (int kt = 0; kt < 4; ++kt) tile_step(kt, q8A, oA, bbA);
  #pragma unroll
  for (int kt = 0; kt < 4; ++kt) tile_step(kt, q8B, oB, bbB);

  // Phase-2 staging: kv rows 128..255 (loads long complete)
  stage(row0 + 128, kc, vc);
  stage(row0 + 192, kd, vd);
  __syncthreads();

  // ---- Phase 2 compute: kt 4..7 ----
  #pragma unroll
  for (int kt = 4; kt < 8; ++kt) tile_step(kt, q8A, oA, bbA);
  #pragma unroll
  for (int kt = 4; kt < 8; ++kt) tile_step(kt, q8B, oB, bbB);

  // denominator: C row16 = reg8 of hi=0 lanes; broadcast to both halves
  {
    const float inv = 1.0f / __shfl(oA[8], q32);
    float* op = out + (size_t)(b * 256 + qbaseA + q32) * 512 + h * 16 + hi * 4;
    float4 r0 = { oA[0] * inv, oA[1] * inv, oA[2] * inv, oA[3] * inv };
    float4 r1 = { oA[4] * inv, oA[5] * inv, oA[6] * inv, oA[7] * inv };
    *(float4*)op = r0;
    *(float4*)(op + 8) = r1;
  }
  {
    const float inv = 1.0f / __shfl(oB[8], q32);
    float* op = out + (size_t)(b * 256 + qbaseB + q32) * 512 + h * 16 + hi * 4;
    float4 r0 = { oB[0] * inv, oB[1] * inv, oB[2] * inv, oB[3] * inv };
    float4 r1 = { oB[4] * inv, oB[5] * inv, oB[6] * inv, oB[7] * inv };
    *(float4*)op = r0;
    *(float4*)(op + 8) = r1;
  }
}

extern "C" void kernel_launch(void* const* d_in, const int* in_sizes, int n_in,
                              void* d_out, int out_size, void* d_ws, size_t ws_size,
                              hipStream_t stream) {
  (void)in_sizes; (void)n_in; (void)out_size; (void)d_ws; (void)ws_size;
  const float* inp = (const float*)d_in[0];
  const float* tbl = (const float*)d_in[1];
  float* out = (float*)d_out;
  hipLaunchKernelGGL(mhsa_kernel, dim3(2048), dim3(256), 0, stream, inp, tbl, out);
}